// Round 3
// baseline (1672.577 us; speedup 1.0000x reference)
//
#include <hip/hip_runtime.h>
#include <hip/hip_bf16.h>
#include <cstdint>

// Fused LISTA v2: block = 64 batch rows, 512 threads (8 waves x 128 cols).
// Z tile in LDS (128 KB, XOR-swizzled — verified correct R1/R2).
// Fixes vs R2 (which scratch-spilled ~40 regs -> 1.15 GB HBM fetch):
//  - B tile no longer in registers: packed bf16 in ws, coalesced b128
//    reload per epilogue (frees 64 regs).
//  - S fragments register-double-buffered: prefetch kc+1 before MFMA(kc),
//    so waitcnt is vmcnt(8) not vmcnt(0) (AITER pattern).
// Combined reg budget ~236 < 256 (2 waves/SIMD) -> no spill.

typedef __attribute__((ext_vector_type(8))) short short8;   // 8 x bf16
typedef __attribute__((ext_vector_type(4))) float floatx4;  // mfma acc
typedef __attribute__((ext_vector_type(4))) unsigned int uintx4;

__device__ __forceinline__ unsigned short f2b(float f) {
    __hip_bfloat16 h = __float2bfloat16(f);
    return *(unsigned short*)&h;
}
__device__ __forceinline__ float b2f(unsigned short u) {
    union { unsigned int i; float f; } x; x.i = ((unsigned int)u) << 16; return x.f;
}

__global__ void __launch_bounds__(512, 2)
lista_fused(const unsigned short* __restrict__ Xbf,   // 16384 x 256
            const unsigned short* __restrict__ Webf,  // 1024 x 256
            const unsigned short* __restrict__ Sbf,   // 1024 x 1024
            const float* __restrict__ theta,          // 1024
            uintx4* __restrict__ Bws,                 // packed B tile, 32 MB
            float* __restrict__ out)                  // 16384 x 1024 fp32
{
    __shared__ __align__(16) unsigned short Zd[64 * 1024];  // 128 KB

    const int t    = threadIdx.x;
    const int wave = t >> 6;        // 0..7, owns cols [wave*128, +128)
    const int lane = t & 63;
    const int l15  = lane & 15;
    const int q    = lane >> 4;
    const int blk  = blockIdx.x;    // 0..255, owns rows [blk*64, +64)

    floatx4 acc[4][8];              // 128 AGPR
#pragma unroll
    for (int mi = 0; mi < 4; ++mi)
#pragma unroll
        for (int ni = 0; ni < 8; ++ni) acc[mi][ni] = (floatx4){0.f, 0.f, 0.f, 0.f};

    // A/B-operand frag layout: lane -> 16B at [m|n = l15][k = q*8 .. q*8+7]
    const char* Sb = (const char*)Sbf  + ((size_t)(wave * 128 + l15) * 1024 + q * 8) * 2;
    const char* Xb = (const char*)Xbf  + ((size_t)(blk * 64   + l15) * 256  + q * 8) * 2;
    const char* Wb = (const char*)Webf + ((size_t)(wave * 128 + l15) * 256  + q * 8) * 2;

    // ---- init GEMM: acc = X @ We^T  (K=256, frags direct from global) ----
#pragma unroll
    for (int kc = 0; kc < 8; ++kc) {
        short8 af[4], sf[8];
#pragma unroll
        for (int mi = 0; mi < 4; ++mi)
            af[mi] = *(const short8*)(Xb + mi * 8192 + kc * 64);
#pragma unroll
        for (int ni = 0; ni < 8; ++ni)
            sf[ni] = *(const short8*)(Wb + ni * 8192 + kc * 64);
#pragma unroll
        for (int mi = 0; mi < 4; ++mi)
#pragma unroll
            for (int ni = 0; ni < 8; ++ni)
                acc[mi][ni] = __builtin_amdgcn_mfma_f32_16x16x32_bf16(
                    af[mi], sf[ni], acc[mi][ni], 0, 0, 0);
    }

    float th[8];
#pragma unroll
    for (int ni = 0; ni < 8; ++ni) th[ni] = theta[wave * 128 + ni * 16 + l15];

    // ---- init epilogue: Bws = pack(B); Z0 = eta(B) -> LDS; acc := round(B) ----
#pragma unroll
    for (int mi = 0; mi < 4; ++mi) {
#pragma unroll
        for (int c = 0; c < 4; ++c) {
            uintx4 pk;
#pragma unroll
            for (int e = 0; e < 4; ++e) {
                const int j0 = c * 8 + e * 2, j1 = j0 + 1;
                const unsigned short b0 = f2b(acc[mi][j0 >> 2][j0 & 3]);
                const unsigned short b1 = f2b(acc[mi][j1 >> 2][j1 & 3]);
                pk[e] = (unsigned int)b0 | ((unsigned int)b1 << 16);
            }
            Bws[(size_t)((blk * 4 + mi) * 4 + c) * 512 + t] = pk;
        }
#pragma unroll
        for (int ni = 0; ni < 8; ++ni) {
            const int col   = wave * 128 + ni * 16 + l15;
            const int chunk = col >> 3;
            const int coff  = (col & 7) * 2;
#pragma unroll
            for (int v = 0; v < 4; ++v) {
                const unsigned short bb = f2b(acc[mi][ni][v]);
                const float c0 = b2f(bb);
                acc[mi][ni][v] = c0;                 // acc := rounded B
                const float a = fabsf(c0) - th[ni];
                const float z = a > 0.f ? copysignf(a, c0) : 0.f;
                const int r = mi * 16 + q * 4 + v;
                const int s = (chunk & ~7) | ((chunk ^ r) & 7);
                *(unsigned short*)((char*)Zd + r * 2048 + s * 16 + coff) = f2b(z);
            }
        }
    }
    __syncthreads();

    // ---- 16 fused steps ----
#pragma unroll 1
    for (int step = 1; step <= 16; ++step) {
        short8 sb[2][8];                 // S frag double buffer (64 VGPR)
#pragma unroll
        for (int ni = 0; ni < 8; ++ni)   // preload kc = 0
            sb[0][ni] = *(const short8*)(Sb + ni * 32768);

#pragma unroll 8
        for (int kc = 0; kc < 32; ++kc) {
            const int cur = kc & 1, nxt = cur ^ 1;
            const int kn  = (kc + 1) & 31;          // wrap: branchless, in-bounds
#pragma unroll
            for (int ni = 0; ni < 8; ++ni)          // prefetch kc+1 BEFORE MFMA(kc)
                sb[nxt][ni] = *(const short8*)(Sb + ni * 32768 + kn * 64);

            short8 af[4];
#pragma unroll
            for (int mi = 0; mi < 4; ++mi) {
                const int row = mi * 16 + l15;
                const int c   = kc * 4 + q;
                const int s   = (c & ~7) | ((c ^ row) & 7);
                af[mi] = *(const short8*)((const char*)Zd + row * 2048 + s * 16);
            }
#pragma unroll
            for (int mi = 0; mi < 4; ++mi)
#pragma unroll
                for (int ni = 0; ni < 8; ++ni)
                    acc[mi][ni] = __builtin_amdgcn_mfma_f32_16x16x32_bf16(
                        af[mi], sb[cur][ni], acc[mi][ni], 0, 0, 0);
        }
        __syncthreads();   // all waves done reading old Z

        if (step < 16) {
#pragma unroll
            for (int mi = 0; mi < 4; ++mi) {
                uintx4 pk[4];
#pragma unroll
                for (int c = 0; c < 4; ++c)
                    pk[c] = Bws[(size_t)((blk * 4 + mi) * 4 + c) * 512 + t];
#pragma unroll
                for (int ni = 0; ni < 8; ++ni) {
                    const int col   = wave * 128 + ni * 16 + l15;
                    const int chunk = col >> 3;
                    const int coff  = (col & 7) * 2;
#pragma unroll
                    for (int v = 0; v < 4; ++v) {
                        const float cv = acc[mi][ni][v];
                        const float a  = fabsf(cv) - th[ni];
                        const float z  = a > 0.f ? copysignf(a, cv) : 0.f;
                        const int r = mi * 16 + q * 4 + v;
                        const int s = (chunk & ~7) | ((chunk ^ r) & 7);
                        *(unsigned short*)((char*)Zd + r * 2048 + s * 16 + coff) = f2b(z);
                        const int j = ni * 4 + v;
                        const unsigned int u = pk[j >> 3][(j & 7) >> 1];
                        acc[mi][ni][v] = b2f((j & 1) ? (unsigned short)(u >> 16)
                                                     : (unsigned short)(u & 0xffff));
                    }
                }
            }
            __syncthreads();   // new Z visible before next step reads
        } else {
#pragma unroll
            for (int mi = 0; mi < 4; ++mi)
#pragma unroll
                for (int ni = 0; ni < 8; ++ni) {
                    const int col = wave * 128 + ni * 16 + l15;
#pragma unroll
                    for (int v = 0; v < 4; ++v) {
                        const float cv = acc[mi][ni][v];
                        const float a  = fabsf(cv) - th[ni];
                        const float z  = a > 0.f ? copysignf(a, cv) : 0.f;
                        const int r = mi * 16 + q * 4 + v;
                        out[(size_t)(blk * 64 + r) * 1024 + col] = z;
                    }
                }
        }
    }
}

__global__ void __launch_bounds__(256)
cvt4(const float* __restrict__ s, unsigned short* __restrict__ d, int n4)
{
    const int i = blockIdx.x * blockDim.x + threadIdx.x;
    if (i < n4) {
        const float4 v = ((const float4*)s)[i];
        ushort4 o;
        o.x = f2b(v.x); o.y = f2b(v.y); o.z = f2b(v.z); o.w = f2b(v.w);
        ((ushort4*)d)[i] = o;
    }
}

extern "C" void kernel_launch(void* const* d_in, const int* in_sizes, int n_in,
                              void* d_out, int out_size, void* d_ws, size_t ws_size,
                              hipStream_t stream) {
    const float* X     = (const float*)d_in[0];  // 16384 x 256
    const float* We    = (const float*)d_in[1];  // 1024 x 256
    const float* S     = (const float*)d_in[2];  // 1024 x 1024
    const float* theta = (const float*)d_in[3];  // 1024
    float* out = (float*)d_out;                  // 16384 x 1024 fp32

    char* ws = (char*)d_ws;
    unsigned short* S_bf  = (unsigned short*)(ws);                          // 2 MB
    unsigned short* X_bf  = (unsigned short*)(ws + (size_t)3  * 1048576);   // 8 MB
    unsigned short* We_bf = (unsigned short*)(ws + (size_t)11 * 1048576);   // 0.5 MB
    uintx4*         Bws   = (uintx4*)        (ws + (size_t)12 * 1048576);   // 32 MB

    cvt4<<<dim3(1024), dim3(256), 0, stream>>>(S,  S_bf,  1024 * 1024 / 4);
    cvt4<<<dim3(4096), dim3(256), 0, stream>>>(X,  X_bf,  16384 * 256 / 4);
    cvt4<<<dim3(256),  dim3(256), 0, stream>>>(We, We_bf, 1024 * 256 / 4);

    lista_fused<<<dim3(256), dim3(512), 0, stream>>>(X_bf, We_bf, S_bf, theta, Bws, out);
}